// Round 1
// baseline (187.356 us; speedup 1.0000x reference)
//
#include <hip/hip_runtime.h>
#include <math.h>

#define DD 128          // embed dim
#define DEG 16          // neighbors
#define TM 16           // node tile per block (grid = 50000/16 = 3125 exactly)
#define LDST 136        // LDS row stride in f16
#define EPSV 1e-5f

typedef _Float16 half4_t __attribute__((ext_vector_type(4)));
typedef _Float16 half8_t __attribute__((ext_vector_type(8)));
typedef float    f32x4   __attribute__((ext_vector_type(4)));

// fast tanh(n)/n, n >= EPSV. __expf maps to v_exp_f32; graceful at large n (2/inf -> 0).
__device__ __forceinline__ float fast_tanh_over(float n) {
    float e  = __expf(2.f * n);
    float th = 1.f - __fdividef(2.f, e + 1.f);
    return __fdividef(th, n);
}
// fast atanh(n)/n, n in [EPSV, 1-EPSV]
__device__ __forceinline__ float fast_atanh_over(float n) {
    float r = 0.5f * __logf(__fdividef(1.f + n, 1.f - n));
    return __fdividef(r, n);
}

// ---- prep (single kernel): x16[s] = x[s]*mask[s]^2 (f16), plus W->f16 transpose.
// Folding mask^2 removes all mask gathers: msg[s] = m_s*((m_s*x[s])@W) = (m_s^2*x[s])@W.
__global__ void prep(const float* __restrict__ x, const float* __restrict__ mask,
                     _Float16* __restrict__ x16, int n4, int xb,
                     const float* __restrict__ Wp, const float* __restrict__ Wn,
                     _Float16* __restrict__ WT)
{
    if ((int)blockIdx.x < xb) {
        int i = blockIdx.x * blockDim.x + threadIdx.x;
        if (i >= n4) return;
        float m = mask[i >> 5];            // 32 half4 groups per row
        float m2 = m * m;
        float4 v = ((const float4*)x)[i];
        half4_t h;
        h[0] = (_Float16)(v.x * m2); h[1] = (_Float16)(v.y * m2);
        h[2] = (_Float16)(v.z * m2); h[3] = (_Float16)(v.w * m2);
        ((half4_t*)x16)[i] = h;
    } else {
        // 32 blocks: mat = (l,rel) in WT order [l0p, l0n, l1p, l1n], 8 chunks each
        int bid   = blockIdx.x - xb;
        int mat   = bid >> 3;              // 0..3
        int chunk = bid & 7;
        int l = mat >> 1, rel = mat & 1;
        const float* __restrict__ src = (rel ? Wn : Wp) + (size_t)l * DD * DD;
        _Float16* __restrict__ dst = WT + (size_t)mat * DD * DD;
        for (int o = chunk * 2048 + threadIdx.x; o < chunk * 2048 + 2048; o += 256) {
            int nn = o >> 7, kk = o & 127;
            dst[o] = (_Float16)src[kk * DD + nn];   // WT[n][k] (transposed)
        }
    }
}

// ---- one fused GNN layer ----
// launch_bounds(256,2): relax VGPR cap 64 -> ~128 so all 16 gathers stay in
// flight per lane (the 64-VGPR build strip-mined them into ~4-deep batches ->
// latency-bound at ~44 outstanding loads/CU; we need ~4x that).
__global__ __launch_bounds__(256, 2) void fused_layer(
    const _Float16* __restrict__ src16,          // pre-scaled by mask^2
    const int*   __restrict__ adj, const float* __restrict__ wgt,
    const float* __restrict__ mask,
    const _Float16* __restrict__ WTp, const _Float16* __restrict__ WTn,
    float* __restrict__ dst_f32, _Float16* __restrict__ dst_f16,
    int n, int apply_logmap)
{
    __shared__ __align__(16) _Float16 aggP[TM][LDST];   // 4.25 KB
    __shared__ __align__(16) _Float16 aggN[TM][LDST];   // 4.25 KB
    __shared__ float partA[4][TM];                       // cross-wave norm partials
    __shared__ float partB[4][TM];

    const int row0 = blockIdx.x * TM;
    const int tid  = threadIdx.x;
    const int qw   = tid >> 4;         // quarter-wave 0..15 -> owns node row qw
    const int l16  = tid & 15;         // covers cols [8*l16, 8*l16+8)

    // ---- phase 1: gather-aggregate; ALL 16 edges in flight (16B/lane loads) ----
    float aP[8] = {0.f,0.f,0.f,0.f,0.f,0.f,0.f,0.f};
    float aN[8] = {0.f,0.f,0.f,0.f,0.f,0.f,0.f,0.f};
    const int node = row0 + qw;
    if (node < n) {
        const int*   __restrict__ arow = adj + (size_t)node * DEG;
        const float* __restrict__ wrow = wgt + (size_t)node * DEG;
        int   idxs[16];
        float ws[16];
        #pragma unroll
        for (int b = 0; b < 4; ++b) {
            int4   ia = ((const int4*)arow)[b];
            float4 wa = ((const float4*)wrow)[b];
            idxs[b*4+0] = ia.x; idxs[b*4+1] = ia.y; idxs[b*4+2] = ia.z; idxs[b*4+3] = ia.w;
            ws[b*4+0] = wa.x; ws[b*4+1] = wa.y; ws[b*4+2] = wa.z; ws[b*4+3] = wa.w;
        }
        half8_t v[16];                  // 16 independent 16B gathers in flight
        #pragma unroll
        for (int j = 0; j < 16; ++j)
            v[j] = *(const half8_t*)(src16 + (size_t)idxs[j] * DD + l16 * 8);
        #pragma unroll
        for (int j = 0; j < 16; ++j) {
            float wp = fmaxf(ws[j], 0.f);
            float wn = fmaxf(-ws[j], 0.f);
            #pragma unroll
            for (int c = 0; c < 8; ++c) {
                float f = (float)v[j][c];
                aP[c] += wp * f;
                aN[c] += wn * f;
            }
        }
    }
    half8_t hP, hN;
    #pragma unroll
    for (int c = 0; c < 8; ++c) { hP[c] = (_Float16)aP[c]; hN[c] = (_Float16)aN[c]; }
    *(half8_t*)&aggP[qw][l16 * 8] = hP;
    *(half8_t*)&aggN[qw][l16 * 8] = hN;
    __syncthreads();

    // ---- phase 2: MFMA. 4 waves split the 8 n-blocks (2 each); rows shared ----
    const int wv2  = tid >> 6;       // wave 0..3
    const int l64  = tid & 63;
    const int l15  = l64 & 15;
    const int quad = l64 >> 4;

    half8_t aPf[4], aNf[4];          // A[m=l15][k=kb*32+quad*8+j]
    #pragma unroll
    for (int kb = 0; kb < 4; ++kb) {
        aPf[kb] = *(const half8_t*)&aggP[l15][kb * 32 + quad * 8];
        aNf[kb] = *(const half8_t*)&aggN[l15][kb * 32 + quad * 8];
    }

    f32x4 acc[2];
    acc[0] = (f32x4){0.f, 0.f, 0.f, 0.f};
    acc[1] = (f32x4){0.f, 0.f, 0.f, 0.f};
    #pragma unroll
    for (int t = 0; t < 2; ++t) {
        const int nb = wv2 * 2 + t;
        const _Float16* bp = WTp + (size_t)(nb * 16 + l15) * DD + quad * 8;
        const _Float16* bn = WTn + (size_t)(nb * 16 + l15) * DD + quad * 8;
        #pragma unroll
        for (int kb = 0; kb < 4; ++kb) {
            acc[t] = __builtin_amdgcn_mfma_f32_16x16x32_f16(
                aPf[kb], *(const half8_t*)(bp + kb * 32), acc[t], 0, 0, 0);
            acc[t] = __builtin_amdgcn_mfma_f32_16x16x32_f16(
                aNf[kb], *(const half8_t*)(bn + kb * 32), acc[t], 0, 0, 0);
        }
    }

    // ---- phase 3: epilogue. C/D: row=quad*4+r, cols wv2*32 + {l15, 16+l15} ----
    float cv0[4], cv1[4], mr[4];
    #pragma unroll
    for (int r = 0; r < 4; ++r) {
        const int rl  = quad * 4 + r;
        const int row = row0 + rl;
        float m = (row < n) ? mask[row] : 0.f;
        mr[r] = m;
        float c0 = acc[0][r] * m, c1 = acc[1][r] * m;
        cv0[r] = c0; cv1[r] = c1;
        float p = c0 * c0 + c1 * c1;
        p += __shfl_xor(p, 1); p += __shfl_xor(p, 2);
        p += __shfl_xor(p, 4); p += __shfl_xor(p, 8);   // within 16-lane group
        if (l15 == 0) partA[wv2][rl] = p;
    }
    __syncthreads();

    float x0[4], x1[4];
    #pragma unroll
    for (int r = 0; r < 4; ++r) {
        const int rl = quad * 4 + r;
        float c2 = partA[0][rl] + partA[1][rl] + partA[2][rl] + partA[3][rl];
        float nc = fmaxf(sqrtf(c2), EPSV);
        float sc = fast_tanh_over(nc);
        float m  = mr[r];
        float t0 = fmaxf(cv0[r] * sc * m, 0.f) * m;      // expmap*m, relu, *m
        float t1 = fmaxf(cv1[r] * sc * m, 0.f) * m;
        x0[r] = t0; x1[r] = t1;
        if (apply_logmap) {                               // uniform branch
            float p = t0 * t0 + t1 * t1;
            p += __shfl_xor(p, 1); p += __shfl_xor(p, 2);
            p += __shfl_xor(p, 4); p += __shfl_xor(p, 8);
            if (l15 == 0) partB[wv2][rl] = p;
        }
    }

    if (apply_logmap) {
        __syncthreads();
        #pragma unroll
        for (int r = 0; r < 4; ++r) {
            const int rl  = quad * 4 + r;
            const int row = row0 + rl;
            if (row >= n) continue;
            float s2  = partB[0][rl] + partB[1][rl] + partB[2][rl] + partB[3][rl];
            float nc2 = fminf(fmaxf(sqrtf(s2), EPSV), 1.f - EPSV);
            // store logmap(x)*mask^2 so the next layer's gather needs no mask
            float f = fast_atanh_over(nc2) * mr[r] * mr[r];
            _Float16* drow = dst_f16 + (size_t)row * DD + wv2 * 32 + l15;
            drow[0]  = (_Float16)(x0[r] * f);
            drow[16] = (_Float16)(x1[r] * f);
        }
    } else {
        #pragma unroll
        for (int r = 0; r < 4; ++r) {
            const int rl  = quad * 4 + r;
            const int row = row0 + rl;
            if (row >= n) continue;
            float* drow = dst_f32 + (size_t)row * DD + wv2 * 32 + l15;
            drow[0]  = x0[r];
            drow[16] = x1[r];
        }
    }
}

extern "C" void kernel_launch(void* const* d_in, const int* in_sizes, int n_in,
                              void* d_out, int out_size, void* d_ws, size_t ws_size,
                              hipStream_t stream)
{
    const float* node_repr = (const float*)d_in[0];
    const int*   adj       = (const int*)  d_in[1];
    const float* weight    = (const float*)d_in[2];
    const float* mask      = (const float*)d_in[3];
    const float* W_pos     = (const float*)d_in[4];   // [L,128,128]
    const float* W_neg     = (const float*)d_in[5];

    const int n = in_sizes[0] / DD;                   // 50000

    _Float16* x16 = (_Float16*)d_ws;                  // n*128 f16
    _Float16* y16 = x16 + (size_t)n * DD;             // n*128 f16
    _Float16* WT  = y16 + (size_t)n * DD;             // 4 * 128*128 f16

    const int n4 = n * DD / 4;
    const int xb = (n4 + 255) / 256;
    prep<<<xb + 32, 256, 0, stream>>>(node_repr, mask, x16, n4, xb,
                                      W_pos, W_neg, WT);

    dim3 grid((n + TM - 1) / TM);
    // layer 0
    fused_layer<<<grid, 256, 0, stream>>>(x16, adj, weight, mask,
                                          WT + 0 * DD * DD, WT + 1 * DD * DD,
                                          nullptr, y16, n, 1);
    // layer 1
    fused_layer<<<grid, 256, 0, stream>>>(y16, adj, weight, mask,
                                          WT + 2 * DD * DD, WT + 3 * DD * DD,
                                          (float*)d_out, nullptr, n, 0);
}